// Round 6
// baseline (156.619 us; speedup 1.0000x reference)
//
#include <hip/hip_runtime.h>
#include <hip/hip_fp16.h>

// Idealizer: torsion angles + backbone frames -> atom14 coordinates.
// One thread per residue; block computes a 256-residue tile into LDS
// (atoms 4..13 only), then copies out coalesced (backbone re-read from bb).
//
// R1: 176 VGPR reg-buffered -> 93 us. R2: forced 64 VGPR -> spill, 159 us.
// R4: scattered dword stores -> WRITE 266 MB (partial-line amplification).
// R5: 42-float LDS tile -> WRITE clean 82 MB, but 57 KB LDS -> 2 blocks/CU,
//     occupancy 18.5%, VALUBusy 34%, latency-bound at 63 us.
// R6: 30-float tile + fp16 default_frames (37.5 KB -> 4 blocks/CU) +
//     local-frame reassociation (B applied once per atom, g<=4 needs no
//     3x3 compose) + __launch_bounds__(256,4) (cap 128, natural was 88).

struct F3 { float x, y, z; };

__device__ __forceinline__ F3 f3sub(F3 a, F3 b) { return {a.x-b.x, a.y-b.y, a.z-b.z}; }
__device__ __forceinline__ F3 f3cross(F3 a, F3 b) {
    return {a.y*b.z - a.z*b.y, a.z*b.x - a.x*b.z, a.x*b.y - a.y*b.x};
}
__device__ __forceinline__ float f3dot(F3 a, F3 b) { return a.x*b.x + a.y*b.y + a.z*b.z; }

// sin/cos of the dihedral angle directly (reference takes sincos(atan2(y,x))).
__device__ __forceinline__ void dihedral_sc(F3 p0, F3 p1, F3 p2, F3 p3,
                                            float& s, float& c) {
    F3 b0 = f3sub(p0, p1);          // -(p1 - p0)
    F3 b1 = f3sub(p2, p1);
    F3 b2 = f3sub(p3, p2);
    F3 u = f3cross(b0, b1);
    F3 v = f3cross(b2, b1);         // ref's "b1xb2" is cross(b2, b1)
    F3 w = f3cross(u, v);
    float y = f3dot(w, b1) * rsqrtf(fmaxf(f3dot(b1, b1), 1e-30f));
    float x = f3dot(u, v);
    float r2 = x*x + y*y;
    if (r2 > 1e-24f) {
        float rinv = rsqrtf(r2);
        s = y * rinv;
        c = x * rinv;
    } else {                        // atan2(0,0)=0 -> angle 0
        s = 0.0f;
        c = 1.0f;
    }
}

#define LIT_STRIDE 30   // atoms 4..13, packed
#define OT_STRIDE  30   // output tile row: atoms 4..13

__global__ __launch_bounds__(256, 4) void idealizer_kernel(
    const int*   __restrict__ aa,       // (n,)
    const float* __restrict__ bb,       // (n,4,3)
    const float* __restrict__ tor,      // (n,4)
    const float* __restrict__ dframes,  // (21,8,4,4)
    const int*   __restrict__ gidx,     // (21,14)
    const float* __restrict__ amask,    // (21,14)
    const float* __restrict__ lit,      // (21,14,3)
    float*       __restrict__ out,      // (n,14,3)
    int n)
{
    __shared__ __align__(16) float  s_ot[256 * OT_STRIDE];   // 30720 B
    __shared__ __align__(8)  __half s_dfh[21 * 8 * 12];      //  4032 B (rows 0..2 of each 4x4)
    __shared__ __align__(16) float  s_lit[21 * LIT_STRIDE];  //  2520 B
    __shared__ unsigned s_gpk[21];   // 10 x 3-bit group ids (atoms 4..13)
    __shared__ unsigned s_mbit[21];  // 10 x 1-bit atom mask (atoms 4..13)

    const int tid = threadIdx.x;
    // default_frames: keep rows 0..2 (12 of 16 floats per frame), as fp16
    for (int j = tid; j < 21 * 8 * 12; j += 256) {
        int blk = j / 12, e = j - blk * 12;          // e = row*4+col, row<3
        s_dfh[j] = __float2half(dframes[blk * 16 + e]);
    }
    for (int j = tid; j < 21 * 30; j += 256) {
        int a = j / 30, r = j - a * 30;
        s_lit[a * LIT_STRIDE + r] = lit[a * 42 + 12 + r];
    }
    if (tid < 21) {
        unsigned gp = 0, mb = 0;
        #pragma unroll
        for (int a = 0; a < 10; a++) {
            gp |= ((unsigned)gidx[tid * 14 + 4 + a]) << (3 * a);
            mb |= (amask[tid * 14 + 4 + a] != 0.0f ? 1u : 0u) << a;
        }
        s_gpk[tid] = gp;
        s_mbit[tid] = mb;
    }
    __syncthreads();

    for (int i0 = blockIdx.x * 256; i0 < n; i0 += gridDim.x * 256) {
        const int i = i0 + tid;
        if (i < n) {
            // ---- own residue backbone (N, CA, C = floats 0..8) ----
            const float4* bb4 = (const float4*)bb;
            float4 q0 = bb4[i * 3 + 0];   // N.xyz, CA.x
            float4 q1 = bb4[i * 3 + 1];   // CA.yz, C.xy
            float Cz  = bb[i * 12 + 8];
            F3 Np  = {q0.x, q0.y, q0.z};
            F3 CAp = {q0.w, q1.x, q1.y};
            F3 Cp  = {q1.z, q1.w, Cz};

            // ---- neighbors (clamped; boundary angles overridden below) ----
            const int im = (i > 0)     ? i - 1 : 0;
            const int ip = (i < n - 1) ? i + 1 : 0;
            F3 Cm = { bb[im * 12 + 6], bb[im * 12 + 7], bb[im * 12 + 8] };  // C[i-1]
            float4 r0 = bb4[ip * 3 + 0];                                     // N[i+1], CA[i+1].x
            float2 r1 = ((const float2*)bb)[ip * 6 + 2];                     // CA[i+1].yz
            F3 Nn  = {r0.x, r0.y, r0.z};
            F3 CAn = {r0.w, r1.x, r1.y};

            // ---- backbone dihedrals (sin/cos directly) ----
            float s_ph, c_ph, s_ps, c_ps, s_om, c_om;
            dihedral_sc(Cm,  Np,  CAp, Cp,  s_ph, c_ph);   // phi
            dihedral_sc(Np,  CAp, Cp,  Nn,  s_ps, c_ps);   // psi
            dihedral_sc(CAp, Cp,  Nn,  CAn, s_om, c_om);   // omega
            if (i == 0)     { s_ph = 0.0f; c_ph = 1.0f; }
            if (i == n - 1) { s_ps = 0.0f; c_ps = 1.0f; s_om = 0.0f; c_om = 1.0f; }

            // ---- backbone frame from reference (N, CA, C) ----
            const float eps = 1e-20f;
            F3 nv = f3sub(Np, CAp);
            F3 cv = f3sub(Cp, CAp);
            float cx = cv.x, cy = cv.y, cz = cv.z;
            float d2xy  = cx * cx + cy * cy;
            float inrm  = rsqrtf(eps + d2xy);
            float s1 = -cy * inrm, c1 = cx * inrm;
            float inrm2 = rsqrtf(eps + d2xy + cz * cz);
            float s2v = cz * inrm2, c2v = sqrtf(d2xy) * inrm2;
            float Rc00 = c2v * c1,  Rc01 = -c2v * s1, Rc02 = s2v;
            float Rc10 = s1,        Rc11 = c1,        Rc12 = 0.0f;
            float Rc20 = -s2v * c1, Rc21 = s2v * s1,  Rc22 = c2v;
            float n2y = Rc10 * nv.x + Rc11 * nv.y + Rc12 * nv.z;
            float n2z = Rc20 * nv.x + Rc21 * nv.y + Rc22 * nv.z;
            float inrm3 = rsqrtf(eps + n2y * n2y + n2z * n2z);
            float sn = -n2z * inrm3, cn = n2y * inrm3;
            float M10 = cn * Rc10 - sn * Rc20, M11 = cn * Rc11 - sn * Rc21, M12 = cn * Rc12 - sn * Rc22;
            float M20 = sn * Rc10 + cn * Rc20, M21 = sn * Rc11 + cn * Rc21, M22 = sn * Rc12 + cn * Rc22;
            // bb_r = (Rn @ Rc)^T
            float B00 = Rc00, B01 = M10, B02 = M20;
            float B10 = Rc01, B11 = M11, B12 = M21;
            float B20 = Rc02, B21 = M12, B22 = M22;

            // ---- per-frame sin/cos: [identity, omega, phi, psi, tor0..3] ----
            float4 tv = ((const float4*)tor)[i];
            float sang[8], cang[8];
            sang[0] = 0.0f; cang[0] = 1.0f;
            sang[1] = s_om; cang[1] = c_om;
            sang[2] = s_ph; cang[2] = c_ph;
            sang[3] = s_ps; cang[3] = c_ps;
            __sincosf(tv.x, &sang[4], &cang[4]);
            __sincosf(tv.y, &sang[5], &cang[5]);
            __sincosf(tv.z, &sang[6], &cang[6]);
            __sincosf(tv.w, &sang[7], &cang[7]);

            const int aai = aa[i];
            const unsigned gpk  = s_gpk[aai];
            const unsigned mbit = s_mbit[aai];
            const float* lrow = &s_lit[aai * LIT_STRIDE];
            float* srow = &s_ot[tid * OT_STRIDE];

            // ---- group chain in LOCAL coords; B applied once per atom ----
            // L_g: local frame of group g (rel. backbone). g<=4: L = fr_g.
            // g>=5: L_g = L_{g-1} @ fr_g (kinematic chain off group 4).
            float L00, L01, L02, L10, L11, L12, L20, L21, L22, Lx, Ly, Lz;
            const __half2* dfa = (const __half2*)(s_dfh + (size_t)aai * 96);
            #pragma unroll
            for (int g = 0; g < 8; g++) {
                // frame rows 0..2 as 6 half2: (m00,m01)(m02,tx)(m10,m11)(m12,ty)(m20,m21)(m22,tz)
                const __half2* dh = dfa + g * 6;
                float2 e0 = __half22float2(dh[0]), e1 = __half22float2(dh[1]);
                float2 e2 = __half22float2(dh[2]), e3 = __half22float2(dh[3]);
                float2 e4 = __half22float2(dh[4]), e5 = __half22float2(dh[5]);
                float m00 = e0.x, m01 = e0.y, m02 = e1.x, tx = e1.y;
                float m10 = e2.x, m11 = e2.y, m12 = e3.x, ty = e3.y;
                float m20 = e4.x, m21 = e4.y, m22 = e5.x, tz = e5.y;
                float sA = sang[g], cA = cang[g];
                // fr = dr @ Ra(angle): col0 = dcol0; col1 = cA*dcol1 + sA*dcol2;
                //                      col2 = cA*dcol2 - sA*dcol1
                float f00 = m00, f01 = cA * m01 + sA * m02, f02 = cA * m02 - sA * m01;
                float f10 = m10, f11 = cA * m11 + sA * m12, f12 = cA * m12 - sA * m11;
                float f20 = m20, f21 = cA * m21 + sA * m22, f22 = cA * m22 - sA * m21;
                if (g <= 4) {
                    L00 = f00; L01 = f01; L02 = f02;
                    L10 = f10; L11 = f11; L12 = f12;
                    L20 = f20; L21 = f21; L22 = f22;
                    Lx = tx; Ly = ty; Lz = tz;
                } else {
                    float n00 = L00 * f00 + L01 * f10 + L02 * f20;
                    float n01 = L00 * f01 + L01 * f11 + L02 * f21;
                    float n02 = L00 * f02 + L01 * f12 + L02 * f22;
                    float n10 = L10 * f00 + L11 * f10 + L12 * f20;
                    float n11 = L10 * f01 + L11 * f11 + L12 * f21;
                    float n12 = L10 * f02 + L11 * f12 + L12 * f22;
                    float n20 = L20 * f00 + L21 * f10 + L22 * f20;
                    float n21 = L20 * f01 + L21 * f11 + L22 * f21;
                    float n22 = L20 * f02 + L21 * f12 + L22 * f22;
                    float ntx = L00 * tx + L01 * ty + L02 * tz + Lx;
                    float nty = L10 * tx + L11 * ty + L12 * tz + Ly;
                    float ntz = L20 * tx + L21 * ty + L22 * tz + Lz;
                    L00 = n00; L01 = n01; L02 = n02;
                    L10 = n10; L11 = n11; L12 = n12;
                    L20 = n20; L21 = n21; L22 = n22;
                    Lx = ntx; Ly = nty; Lz = ntz;
                }

                // atoms whose group == g: q = L@l + Lt; p = B@q + CA; mask; tile
                #pragma unroll
                for (int a = 0; a < 10; a++) {
                    bool sel = ((gpk >> (3 * a)) & 7u) == (unsigned)g;
                    if (sel) {
                        float mk = ((mbit >> a) & 1u) ? 1.0f : 0.0f;
                        float lx = lrow[3*a], ly = lrow[3*a+1], lz = lrow[3*a+2];
                        float qx = fmaf(L00, lx, fmaf(L01, ly, fmaf(L02, lz, Lx)));
                        float qy = fmaf(L10, lx, fmaf(L11, ly, fmaf(L12, lz, Ly)));
                        float qz = fmaf(L20, lx, fmaf(L21, ly, fmaf(L22, lz, Lz)));
                        float px = fmaf(B00, qx, fmaf(B01, qy, fmaf(B02, qz, CAp.x)));
                        float py = fmaf(B10, qx, fmaf(B11, qy, fmaf(B12, qz, CAp.y)));
                        float pz = fmaf(B20, qx, fmaf(B21, qy, fmaf(B22, qz, CAp.z)));
                        float* po = srow + 3 * a;
                        po[0] = mk * px;
                        po[1] = mk * py;
                        po[2] = mk * pz;
                    }
                }
            }
        }

        __syncthreads();

        // ---- coalesced copy-out: floats 0..11 from bb (L2-hot), 12..41 from tile ----
        int m = n - i0; if (m > 256) m = 256;
        const int cnt2 = m * 21;                      // float2 per 42-float row
        float2* gout = (float2*)(out + (size_t)i0 * 42);
        const float2* bbt = (const float2*)(bb + (size_t)i0 * 12);
        for (int off = tid; off < cnt2; off += 256) {
            int r = off / 21, j = off - r * 21;
            float2 val;
            if (j < 6) {
                val = bbt[r * 6 + j];
            } else {
                const float* tp = &s_ot[r * OT_STRIDE + 2 * (j - 6)];  // 8B-aligned
                val = make_float2(tp[0], tp[1]);
            }
            gout[off] = val;
        }

        __syncthreads();   // tile reusable next iteration
    }
}

extern "C" void kernel_launch(void* const* d_in, const int* in_sizes, int n_in,
                              void* d_out, int out_size, void* d_ws, size_t ws_size,
                              hipStream_t stream) {
    const int*   aa  = (const int*)d_in[0];
    const float* bb  = (const float*)d_in[1];
    const float* tor = (const float*)d_in[2];
    const float* df  = (const float*)d_in[3];
    const int*   gi  = (const int*)d_in[4];
    const float* am  = (const float*)d_in[5];
    const float* lp  = (const float*)d_in[6];
    float* outp = (float*)d_out;
    const int n = in_sizes[0];
    int tiles = (n + 255) / 256;
    int blocks = tiles < 1024 ? tiles : 1024;   // 4 blocks/CU x 256 CU resident
    idealizer_kernel<<<blocks, 256, 0, stream>>>(aa, bb, tor, df, gi, am, lp, outp, n);
}

// Round 7
// 153.874 us; speedup vs baseline: 1.0178x; 1.0178x over previous
//
#include <hip/hip_runtime.h>
#include <hip/hip_fp16.h>

// Idealizer: torsion angles + backbone frames -> atom14 coordinates.
// One thread per residue; block computes a 256-residue tile of atoms 4..13
// into LDS, then copies out coalesced (backbone floats come straight from bb).
//
// Journal:
// R1: 176 VGPR reg-buffered -> 93 us. R2: forced 64 VGPR -> spill, 159 us.
// R4: scattered dword stores -> WRITE 266 MB (partial-line amplification).
// R5: 42-float LDS tile -> clean 82 MB writes, 2 blocks/CU, 63 us.
// R6: fp16 frames + 4 blocks/CU -> occupancy 32% but dur 61 us: occupancy NOT
//     binding. Real sinks: (a) if(sel) atom blocks execute for EVERY (g,a)
//     at wave level (P(skip)=(7/8)^64~=2e-4) -> ~2400 wave-insts of placement;
//     (b) fp16 frame layout aa-stride 48 dwords (48%32=16) -> 2 bank
//     positions -> conflicts 4M cycles.
// R7: dense branchless select-placement (13 insts/block), B applied once per
//     atom, fp32 frames at aa-stride 100 (8 bank positions), fp16 lit,
//     shared-cross dihedrals, division-free copy-out.

struct F3 { float x, y, z; };

__device__ __forceinline__ F3 f3sub(F3 a, F3 b) { return {a.x-b.x, a.y-b.y, a.z-b.z}; }
__device__ __forceinline__ F3 f3cross(F3 a, F3 b) {
    return {a.y*b.z - a.z*b.y, a.z*b.x - a.x*b.z, a.x*b.y - a.y*b.x};
}
__device__ __forceinline__ float f3dot(F3 a, F3 b) { return a.x*b.x + a.y*b.y + a.z*b.z; }

// Dihedral sin/cos from two shared bond-crosses A=cross(u_k,u_k+1),
// B=cross(u_k+1,u_k+2) and the middle bond vector. For all three backbone
// dihedrals the reference's (u,v) are (-A,-B), so x=dot(A,B) and
// cross(u,v)=cross(A,B) -- signs cancel.
__device__ __forceinline__ void dihedral_from(F3 A, F3 B, F3 mid,
                                              float& s, float& c) {
    float x = f3dot(A, B);
    F3 w = f3cross(A, B);
    float y = f3dot(w, mid) * rsqrtf(fmaxf(f3dot(mid, mid), 1e-30f));
    float r2 = x * x + y * y;
    float rinv = rsqrtf(r2);
    bool ok = r2 > 1e-24f;
    s = ok ? y * rinv : 0.0f;   // atan2(0,0)=0 -> angle 0
    c = ok ? x * rinv : 1.0f;
}

#define DF_AA     100   // dwords per aa in s_df: 8 frames x 12 + 4 pad
                        // (100%32=4 -> frame reads spread over 8 bank sets)
#define OT_STRIDE 30    // output tile row: atoms 4..13

__global__ __launch_bounds__(256, 3) void idealizer_kernel(
    const int*   __restrict__ aa,       // (n,)
    const float* __restrict__ bb,       // (n,4,3)
    const float* __restrict__ tor,      // (n,4)
    const float* __restrict__ dframes,  // (21,8,4,4)
    const int*   __restrict__ gidx,     // (21,14)
    const float* __restrict__ amask,    // (21,14)
    const float* __restrict__ lit,      // (21,14,3)
    float*       __restrict__ out,      // (n,14,3)
    int n)
{
    __shared__ __align__(16) float  s_ot[256 * OT_STRIDE];  // 30720 B
    __shared__ __align__(16) float  s_df[21 * DF_AA];       //  8400 B
    __shared__ __align__(8)  __half s_lith[21 * 32];        //  1344 B (30 used)
    __shared__ unsigned s_gpk[21];   // 10 x 3-bit group ids (atoms 4..13)
    __shared__ unsigned s_mbit[21];  // 10 x 1-bit atom mask (atoms 4..13)

    const int tid = threadIdx.x;
    // default_frames rows 0..2 (12 of 16 floats) per frame, fp32
    for (int j = tid; j < 21 * 8 * 12; j += 256) {
        int blk = j / 12, e = j - blk * 12;      // blk = aai*8+g
        s_df[(blk >> 3) * DF_AA + (blk & 7) * 12 + e] = dframes[blk * 16 + e];
    }
    for (int j = tid; j < 21 * 30; j += 256) {
        int a = j / 30, r = j - a * 30;
        s_lith[a * 32 + r] = __float2half(lit[a * 42 + 12 + r]);
    }
    if (tid < 21) {
        unsigned gp = 0, mb = 0;
        #pragma unroll
        for (int a = 0; a < 10; a++) {
            gp |= ((unsigned)gidx[tid * 14 + 4 + a]) << (3 * a);
            mb |= (amask[tid * 14 + 4 + a] != 0.0f ? 1u : 0u) << a;
        }
        s_gpk[tid] = gp;
        s_mbit[tid] = mb;
    }
    __syncthreads();

    for (int i0 = blockIdx.x * 256; i0 < n; i0 += gridDim.x * 256) {
        const int i = i0 + tid;
        if (i < n) {
            // ---- own residue backbone (N, CA, C = floats 0..8) ----
            const float4* bb4 = (const float4*)bb;
            float4 q0 = bb4[i * 3 + 0];   // N.xyz, CA.x
            float4 q1 = bb4[i * 3 + 1];   // CA.yz, C.xy
            float Cz  = bb[i * 12 + 8];
            F3 Np  = {q0.x, q0.y, q0.z};
            F3 CAp = {q0.w, q1.x, q1.y};
            F3 Cp  = {q1.z, q1.w, Cz};

            // ---- neighbors (clamped; boundary angles overridden below) ----
            const int im = (i > 0)     ? i - 1 : 0;
            const int ip = (i < n - 1) ? i + 1 : 0;
            F3 Cm = { bb[im * 12 + 6], bb[im * 12 + 7], bb[im * 12 + 8] };  // C[i-1]
            float4 r0 = bb4[ip * 3 + 0];                                     // N[i+1], CA[i+1].x
            float2 r1 = ((const float2*)bb)[ip * 6 + 2];                     // CA[i+1].yz
            F3 Nn  = {r0.x, r0.y, r0.z};
            F3 CAn = {r0.w, r1.x, r1.y};

            // ---- backbone dihedrals via shared bond crosses ----
            // bonds: u1=N-Cm, u2=CA-N, u3=C-CA, u4=Nn-C, u5=CAn-Nn
            F3 u1 = f3sub(Np, Cm);
            F3 u2 = f3sub(CAp, Np);
            F3 u3 = f3sub(Cp, CAp);
            F3 u4 = f3sub(Nn, Cp);
            F3 u5 = f3sub(CAn, Nn);
            F3 c12 = f3cross(u1, u2), c23 = f3cross(u2, u3);
            F3 c34 = f3cross(u3, u4), c45 = f3cross(u4, u5);
            float s_ph, c_ph, s_ps, c_ps, s_om, c_om;
            dihedral_from(c12, c23, u2, s_ph, c_ph);   // phi  = D(Cm,N,CA,C)
            dihedral_from(c23, c34, u3, s_ps, c_ps);   // psi  = D(N,CA,C,Nn)
            dihedral_from(c34, c45, u4, s_om, c_om);   // omega= D(CA,C,Nn,CAn)
            if (i == 0)     { s_ph = 0.0f; c_ph = 1.0f; }
            if (i == n - 1) { s_ps = 0.0f; c_ps = 1.0f; s_om = 0.0f; c_om = 1.0f; }

            // ---- backbone frame from reference (N, CA, C) ----
            const float eps = 1e-20f;
            F3 nv = f3sub(Np, CAp);
            F3 cv = f3sub(Cp, CAp);
            float cx = cv.x, cy = cv.y, cz2 = cv.z;
            float d2xy  = cx * cx + cy * cy;
            float inrm  = rsqrtf(eps + d2xy);
            float s1 = -cy * inrm, c1 = cx * inrm;
            float inrm2 = rsqrtf(eps + d2xy + cz2 * cz2);
            float s2v = cz2 * inrm2, c2v = sqrtf(d2xy) * inrm2;
            float Rc00 = c2v * c1,  Rc01 = -c2v * s1, Rc02 = s2v;
            float Rc10 = s1,        Rc11 = c1,        Rc12 = 0.0f;
            float Rc20 = -s2v * c1, Rc21 = s2v * s1,  Rc22 = c2v;
            float n2y = Rc10 * nv.x + Rc11 * nv.y + Rc12 * nv.z;
            float n2z = Rc20 * nv.x + Rc21 * nv.y + Rc22 * nv.z;
            float inrm3 = rsqrtf(eps + n2y * n2y + n2z * n2z);
            float sn = -n2z * inrm3, cn = n2y * inrm3;
            float M10 = cn * Rc10 - sn * Rc20, M11 = cn * Rc11 - sn * Rc21, M12 = cn * Rc12 - sn * Rc22;
            float M20 = sn * Rc10 + cn * Rc20, M21 = sn * Rc11 + cn * Rc21, M22 = sn * Rc22 * 0.0f + sn * Rc12 + cn * Rc22;
            // (M22 written explicitly below to avoid typo risk)
            M22 = sn * Rc12 + cn * Rc22;
            // bb_r = (Rn @ Rc)^T
            float B00 = Rc00, B01 = M10, B02 = M20;
            float B10 = Rc01, B11 = M11, B12 = M21;
            float B20 = Rc02, B21 = M12, B22 = M22;

            // ---- per-frame sin/cos: [identity, omega, phi, psi, tor0..3] ----
            float4 tv = ((const float4*)tor)[i];
            float sang[8], cang[8];
            sang[0] = 0.0f; cang[0] = 1.0f;
            sang[1] = s_om; cang[1] = c_om;
            sang[2] = s_ph; cang[2] = c_ph;
            sang[3] = s_ps; cang[3] = c_ps;
            __sincosf(tv.x, &sang[4], &cang[4]);
            __sincosf(tv.y, &sang[5], &cang[5]);
            __sincosf(tv.z, &sang[6], &cang[6]);
            __sincosf(tv.w, &sang[7], &cang[7]);

            const int aai = aa[i];
            const unsigned gpk  = s_gpk[aai];
            const unsigned mbit = s_mbit[aai];

            // hoist lit positions (fp16 LDS -> 30 fp32 regs)
            float la[30];
            {
                const __half2* lh = (const __half2*)&s_lith[aai * 32];
                #pragma unroll
                for (int k = 0; k < 15; k++) {
                    float2 t = __half22float2(lh[k]);
                    la[2*k] = t.x; la[2*k+1] = t.y;
                }
            }

            float v[30];
            #pragma unroll
            for (int k = 0; k < 30; k++) v[k] = 0.0f;

            // ---- group chain in LOCAL (backbone-relative) coords ----
            // all_r[g]: g<=4 -> fr_g ; g>=5 -> fr4@fr5@...@fr_g (chain).
            float L00, L01, L02, L10, L11, L12, L20, L21, L22, Lx, Ly, Lz;
            const float* dfa = &s_df[aai * DF_AA];
            #pragma unroll
            for (int g = 0; g < 8; g++) {
                const float4* dfr = (const float4*)(dfa + g * 12);
                float4 d0 = dfr[0], d1 = dfr[1], d2 = dfr[2];  // rows (m,m,m,t)
                float sA = sang[g], cA = cang[g];
                // fr = dr @ Ra(angle): col1' = c*col1 + s*col2, col2' = c*col2 - s*col1
                float f00 = d0.x, f01 = cA * d0.y + sA * d0.z, f02 = cA * d0.z - sA * d0.y;
                float f10 = d1.x, f11 = cA * d1.y + sA * d1.z, f12 = cA * d1.z - sA * d1.y;
                float f20 = d2.x, f21 = cA * d2.y + sA * d2.z, f22 = cA * d2.z - sA * d2.y;
                if (g <= 4) {
                    L00 = f00; L01 = f01; L02 = f02;
                    L10 = f10; L11 = f11; L12 = f12;
                    L20 = f20; L21 = f21; L22 = f22;
                    Lx = d0.w; Ly = d1.w; Lz = d2.w;
                } else {
                    float n00 = L00 * f00 + L01 * f10 + L02 * f20;
                    float n01 = L00 * f01 + L01 * f11 + L02 * f21;
                    float n02 = L00 * f02 + L01 * f12 + L02 * f22;
                    float n10 = L10 * f00 + L11 * f10 + L12 * f20;
                    float n11 = L10 * f01 + L11 * f11 + L12 * f21;
                    float n12 = L10 * f02 + L11 * f12 + L12 * f22;
                    float n20 = L20 * f00 + L21 * f10 + L22 * f20;
                    float n21 = L20 * f01 + L21 * f11 + L22 * f21;
                    float n22 = L20 * f02 + L21 * f12 + L22 * f22;
                    float ntx = L00 * d0.w + L01 * d1.w + L02 * d2.w + Lx;
                    float nty = L10 * d0.w + L11 * d1.w + L12 * d2.w + Ly;
                    float ntz = L20 * d0.w + L21 * d1.w + L22 * d2.w + Lz;
                    L00 = n00; L01 = n01; L02 = n02;
                    L10 = n10; L11 = n11; L12 = n12;
                    L20 = n20; L21 = n21; L22 = n22;
                    Lx = ntx; Ly = nty; Lz = ntz;
                }

                // dense branchless select: local q for atoms whose group == g
                #pragma unroll
                for (int a = 0; a < 10; a++) {
                    bool sel = ((gpk >> (3 * a)) & 7u) == (unsigned)g;
                    float qx = fmaf(L00, la[3*a], fmaf(L01, la[3*a+1], fmaf(L02, la[3*a+2], Lx)));
                    float qy = fmaf(L10, la[3*a], fmaf(L11, la[3*a+1], fmaf(L12, la[3*a+2], Ly)));
                    float qz = fmaf(L20, la[3*a], fmaf(L21, la[3*a+1], fmaf(L22, la[3*a+2], Lz)));
                    v[3*a]   = sel ? qx : v[3*a];
                    v[3*a+1] = sel ? qy : v[3*a+1];
                    v[3*a+2] = sel ? qz : v[3*a+2];
                }
            }

            // ---- apply backbone frame + mask ONCE per atom ----
            #pragma unroll
            for (int a = 0; a < 10; a++) {
                float mk = ((mbit >> a) & 1u) ? 1.0f : 0.0f;
                float qx = v[3*a], qy = v[3*a+1], qz = v[3*a+2];
                v[3*a]   = mk * fmaf(B00, qx, fmaf(B01, qy, fmaf(B02, qz, CAp.x)));
                v[3*a+1] = mk * fmaf(B10, qx, fmaf(B11, qy, fmaf(B12, qz, CAp.y)));
                v[3*a+2] = mk * fmaf(B20, qx, fmaf(B21, qy, fmaf(B22, qz, CAp.z)));
            }

            // ---- tile row write: 15 x ds_write_b64 ----
            float2* so2 = (float2*)&s_ot[tid * OT_STRIDE];
            #pragma unroll
            for (int k = 0; k < 15; k++)
                so2[k] = make_float2(v[2*k], v[2*k+1]);
        }

        __syncthreads();

        // ---- coalesced copy-out, division-free ----
        // out row = 21 float2: j<6 from bb (L2-hot), j>=6 from tile.
        int m = n - i0; if (m > 256) m = 256;
        const int cnt2 = m * 21;
        float2* gout = (float2*)(out + (size_t)i0 * 42);
        const float2* bbt = (const float2*)(bb + (size_t)i0 * 12);
        int r = tid / 21;            // one magic-mul, once
        int j = tid - r * 21;
        for (int off = tid; off < cnt2; off += 256) {
            int bi = (j < 6) ? (r * 6 + j) : 0;        // clamped-safe index
            float2 gval = bbt[bi];
            int tj = (j < 6) ? 0 : (j - 6);
            const float* tp = &s_ot[r * OT_STRIDE + 2 * tj];
            float2 lval = make_float2(tp[0], tp[1]);
            gout[off] = (j < 6) ? gval : lval;
            r += 12; j += 4;                           // 256 = 12*21 + 4
            if (j >= 21) { j -= 21; r += 1; }
        }

        __syncthreads();   // tile reusable next iteration
    }
}

extern "C" void kernel_launch(void* const* d_in, const int* in_sizes, int n_in,
                              void* d_out, int out_size, void* d_ws, size_t ws_size,
                              hipStream_t stream) {
    const int*   aa  = (const int*)d_in[0];
    const float* bb  = (const float*)d_in[1];
    const float* tor = (const float*)d_in[2];
    const float* df  = (const float*)d_in[3];
    const int*   gi  = (const int*)d_in[4];
    const float* am  = (const float*)d_in[5];
    const float* lp  = (const float*)d_in[6];
    float* outp = (float*)d_out;
    const int n = in_sizes[0];
    int tiles = (n + 255) / 256;
    int blocks = tiles < 1024 ? tiles : 1024;   // grid-stride
    idealizer_kernel<<<blocks, 256, 0, stream>>>(aa, bb, tor, df, gi, am, lp, outp, n);
}

// Round 8
// 151.218 us; speedup vs baseline: 1.0357x; 1.0176x over previous
//
#include <hip/hip_runtime.h>
#include <hip/hip_fp16.h>

// Idealizer: torsion angles + backbone frames -> atom14 coordinates.
// One thread per residue; each block computes ONE 256-residue tile of atoms
// 4..13 into LDS, then copies out coalesced (backbone straight from bb).
//
// Journal:
// R1: 176 VGPR reg-buffered -> 93 us. R2: forced 64 VGPR -> spill, 159 us.
// R4: scattered dword stores -> WRITE 266 MB (partial-line amplification).
// R5: LDS tile -> clean 82 MB writes, 2 blocks/CU, 63 us.
// R6: 4 blocks/CU, occupancy 32% -> 61 us (occupancy alone: flat).
// R7: -15% VALU but 3 blocks/CU (LDS 40960 + bounds(256,3)) -> 63 us (flat).
//     Model: dur ~ inst_work / issue_eff(occupancy); must improve BOTH.
//     Bank bug: lit stride 32 halves = 16 dwords -> 2 bank positions.
// R8: R7 insts + 4 blocks/CU (LDS 40716 <= 40960, no reg cap), lit stride
//     34 halves (full bank spread), single-tile blocks (grid 1954).

struct F3 { float x, y, z; };

__device__ __forceinline__ F3 f3sub(F3 a, F3 b) { return {a.x-b.x, a.y-b.y, a.z-b.z}; }
__device__ __forceinline__ F3 f3cross(F3 a, F3 b) {
    return {a.y*b.z - a.z*b.y, a.z*b.x - a.x*b.z, a.x*b.y - a.y*b.x};
}
__device__ __forceinline__ float f3dot(F3 a, F3 b) { return a.x*b.x + a.y*b.y + a.z*b.z; }

// Dihedral sin/cos from two shared bond-crosses A=cross(u_k,u_k+1),
// B=cross(u_k+1,u_k+2) and the middle bond vector (signs cancel vs ref).
__device__ __forceinline__ void dihedral_from(F3 A, F3 B, F3 mid,
                                              float& s, float& c) {
    float x = f3dot(A, B);
    F3 w = f3cross(A, B);
    float y = f3dot(w, mid) * rsqrtf(fmaxf(f3dot(mid, mid), 1e-30f));
    float r2 = x * x + y * y;
    float rinv = rsqrtf(r2);
    bool ok = r2 > 1e-24f;
    s = ok ? y * rinv : 0.0f;   // atan2(0,0)=0 -> angle 0
    c = ok ? x * rinv : 1.0f;
}

#define DF_AA     100   // dwords/aa: 8 frames x 12 + 4 pad; 400B -> 16B-aligned
                        // rows, base bank (4*aai)%32 -> 8 positions
#define LIT_AA    34    // halves/aa: dword offset 17*aai+k -> full bank spread
#define OT_STRIDE 30    // output tile row: atoms 4..13

__global__ __launch_bounds__(256) void idealizer_kernel(
    const int*   __restrict__ aa,       // (n,)
    const float* __restrict__ bb,       // (n,4,3)
    const float* __restrict__ tor,      // (n,4)
    const float* __restrict__ dframes,  // (21,8,4,4)
    const int*   __restrict__ gidx,     // (21,14)
    const float* __restrict__ amask,    // (21,14)
    const float* __restrict__ lit,      // (21,14,3)
    float*       __restrict__ out,      // (n,14,3)
    int n)
{
    __shared__ __align__(16) float  s_ot[256 * OT_STRIDE];  // 30720 B
    __shared__ __align__(16) float  s_df[21 * DF_AA];       //  8400 B
    __shared__ __align__(8)  __half s_lith[21 * LIT_AA];    //  1428 B
    __shared__ unsigned s_gpk[21];   // 10 x 3-bit group ids (atoms 4..13)
    __shared__ unsigned s_mbit[21];  // 10 x 1-bit atom mask (atoms 4..13)
    // total 40716 B -> 4 blocks/CU

    const int tid = threadIdx.x;
    // default_frames rows 0..2 (12 of 16 floats) per frame, fp32
    for (int j = tid; j < 21 * 8 * 12; j += 256) {
        int blk = j / 12, e = j - blk * 12;      // blk = aai*8+g
        s_df[(blk >> 3) * DF_AA + (blk & 7) * 12 + e] = dframes[blk * 16 + e];
    }
    for (int j = tid; j < 21 * 30; j += 256) {
        int a = j / 30, r = j - a * 30;
        s_lith[a * LIT_AA + r] = __float2half(lit[a * 42 + 12 + r]);
    }
    if (tid < 21) {
        unsigned gp = 0, mb = 0;
        #pragma unroll
        for (int a = 0; a < 10; a++) {
            gp |= ((unsigned)gidx[tid * 14 + 4 + a]) << (3 * a);
            mb |= (amask[tid * 14 + 4 + a] != 0.0f ? 1u : 0u) << a;
        }
        s_gpk[tid] = gp;
        s_mbit[tid] = mb;
    }
    __syncthreads();

    const int i0 = blockIdx.x * 256;
    const int i  = i0 + tid;
    if (i < n) {
        // ---- own residue backbone (N, CA, C = floats 0..8) ----
        const float4* bb4 = (const float4*)bb;
        float4 q0 = bb4[i * 3 + 0];   // N.xyz, CA.x
        float4 q1 = bb4[i * 3 + 1];   // CA.yz, C.xy
        float Cz  = bb[i * 12 + 8];
        F3 Np  = {q0.x, q0.y, q0.z};
        F3 CAp = {q0.w, q1.x, q1.y};
        F3 Cp  = {q1.z, q1.w, Cz};

        // ---- neighbors (clamped; boundary angles overridden below) ----
        const int im = (i > 0)     ? i - 1 : 0;
        const int ip = (i < n - 1) ? i + 1 : 0;
        F3 Cm = { bb[im * 12 + 6], bb[im * 12 + 7], bb[im * 12 + 8] };  // C[i-1]
        float4 r0 = bb4[ip * 3 + 0];                                     // N[i+1], CA[i+1].x
        float2 r1 = ((const float2*)bb)[ip * 6 + 2];                     // CA[i+1].yz
        F3 Nn  = {r0.x, r0.y, r0.z};
        F3 CAn = {r0.w, r1.x, r1.y};

        // ---- backbone dihedrals via shared bond crosses ----
        F3 u1 = f3sub(Np, Cm);
        F3 u2 = f3sub(CAp, Np);
        F3 u3 = f3sub(Cp, CAp);
        F3 u4 = f3sub(Nn, Cp);
        F3 u5 = f3sub(CAn, Nn);
        F3 c12 = f3cross(u1, u2), c23 = f3cross(u2, u3);
        F3 c34 = f3cross(u3, u4), c45 = f3cross(u4, u5);
        float s_ph, c_ph, s_ps, c_ps, s_om, c_om;
        dihedral_from(c12, c23, u2, s_ph, c_ph);   // phi
        dihedral_from(c23, c34, u3, s_ps, c_ps);   // psi
        dihedral_from(c34, c45, u4, s_om, c_om);   // omega
        if (i == 0)     { s_ph = 0.0f; c_ph = 1.0f; }
        if (i == n - 1) { s_ps = 0.0f; c_ps = 1.0f; s_om = 0.0f; c_om = 1.0f; }

        // ---- backbone frame from reference (N, CA, C) ----
        const float eps = 1e-20f;
        F3 nv = f3sub(Np, CAp);
        F3 cv = f3sub(Cp, CAp);
        float cx = cv.x, cy = cv.y, cz2 = cv.z;
        float d2xy  = cx * cx + cy * cy;
        float inrm  = rsqrtf(eps + d2xy);
        float s1 = -cy * inrm, c1 = cx * inrm;
        float inrm2 = rsqrtf(eps + d2xy + cz2 * cz2);
        float s2v = cz2 * inrm2, c2v = sqrtf(d2xy) * inrm2;
        float Rc00 = c2v * c1,  Rc01 = -c2v * s1, Rc02 = s2v;
        float Rc10 = s1,        Rc11 = c1,        Rc12 = 0.0f;
        float Rc20 = -s2v * c1, Rc21 = s2v * s1,  Rc22 = c2v;
        float n2y = Rc10 * nv.x + Rc11 * nv.y + Rc12 * nv.z;
        float n2z = Rc20 * nv.x + Rc21 * nv.y + Rc22 * nv.z;
        float inrm3 = rsqrtf(eps + n2y * n2y + n2z * n2z);
        float sn = -n2z * inrm3, cn = n2y * inrm3;
        float M10 = cn * Rc10 - sn * Rc20, M11 = cn * Rc11 - sn * Rc21, M12 = cn * Rc12 - sn * Rc22;
        float M20 = sn * Rc10 + cn * Rc20, M21 = sn * Rc11 + cn * Rc21;
        float M22 = sn * Rc12 + cn * Rc22;
        // bb_r = (Rn @ Rc)^T
        float B00 = Rc00, B01 = M10, B02 = M20;
        float B10 = Rc01, B11 = M11, B12 = M21;
        float B20 = Rc02, B21 = M12, B22 = M22;

        // ---- per-frame sin/cos: [identity, omega, phi, psi, tor0..3] ----
        float4 tv = ((const float4*)tor)[i];
        float sang[8], cang[8];
        sang[0] = 0.0f; cang[0] = 1.0f;
        sang[1] = s_om; cang[1] = c_om;
        sang[2] = s_ph; cang[2] = c_ph;
        sang[3] = s_ps; cang[3] = c_ps;
        __sincosf(tv.x, &sang[4], &cang[4]);
        __sincosf(tv.y, &sang[5], &cang[5]);
        __sincosf(tv.z, &sang[6], &cang[6]);
        __sincosf(tv.w, &sang[7], &cang[7]);

        const int aai = aa[i];
        const unsigned gpk  = s_gpk[aai];
        const unsigned mbit = s_mbit[aai];

        // hoist lit positions (fp16 LDS, full bank spread -> 30 fp32 regs)
        float la[30];
        {
            const __half2* lh = (const __half2*)&s_lith[aai * LIT_AA];
            #pragma unroll
            for (int k = 0; k < 15; k++) {
                float2 t = __half22float2(lh[k]);
                la[2*k] = t.x; la[2*k+1] = t.y;
            }
        }

        float v[30];
        #pragma unroll
        for (int k = 0; k < 30; k++) v[k] = 0.0f;

        // ---- group chain in LOCAL (backbone-relative) coords ----
        float L00, L01, L02, L10, L11, L12, L20, L21, L22, Lx, Ly, Lz;
        const float* dfa = &s_df[aai * DF_AA];
        #pragma unroll
        for (int g = 0; g < 8; g++) {
            const float4* dfr = (const float4*)(dfa + g * 12);
            float4 d0 = dfr[0], d1 = dfr[1], d2 = dfr[2];  // rows (m,m,m,t)
            float sA = sang[g], cA = cang[g];
            // fr = dr @ Ra(angle)
            float f00 = d0.x, f01 = cA * d0.y + sA * d0.z, f02 = cA * d0.z - sA * d0.y;
            float f10 = d1.x, f11 = cA * d1.y + sA * d1.z, f12 = cA * d1.z - sA * d1.y;
            float f20 = d2.x, f21 = cA * d2.y + sA * d2.z, f22 = cA * d2.z - sA * d2.y;
            if (g <= 4) {
                L00 = f00; L01 = f01; L02 = f02;
                L10 = f10; L11 = f11; L12 = f12;
                L20 = f20; L21 = f21; L22 = f22;
                Lx = d0.w; Ly = d1.w; Lz = d2.w;
            } else {
                float n00 = L00 * f00 + L01 * f10 + L02 * f20;
                float n01 = L00 * f01 + L01 * f11 + L02 * f21;
                float n02 = L00 * f02 + L01 * f12 + L02 * f22;
                float n10 = L10 * f00 + L11 * f10 + L12 * f20;
                float n11 = L10 * f01 + L11 * f11 + L12 * f21;
                float n12 = L10 * f02 + L11 * f12 + L12 * f22;
                float n20 = L20 * f00 + L21 * f10 + L22 * f20;
                float n21 = L20 * f01 + L21 * f11 + L22 * f21;
                float n22 = L20 * f02 + L21 * f12 + L22 * f22;
                float ntx = L00 * d0.w + L01 * d1.w + L02 * d2.w + Lx;
                float nty = L10 * d0.w + L11 * d1.w + L12 * d2.w + Ly;
                float ntz = L20 * d0.w + L21 * d1.w + L22 * d2.w + Lz;
                L00 = n00; L01 = n01; L02 = n02;
                L10 = n10; L11 = n11; L12 = n12;
                L20 = n20; L21 = n21; L22 = n22;
                Lx = ntx; Ly = nty; Lz = ntz;
            }

            // dense branchless select: local q for atoms whose group == g
            #pragma unroll
            for (int a = 0; a < 10; a++) {
                bool sel = ((gpk >> (3 * a)) & 7u) == (unsigned)g;
                float qx = fmaf(L00, la[3*a], fmaf(L01, la[3*a+1], fmaf(L02, la[3*a+2], Lx)));
                float qy = fmaf(L10, la[3*a], fmaf(L11, la[3*a+1], fmaf(L12, la[3*a+2], Ly)));
                float qz = fmaf(L20, la[3*a], fmaf(L21, la[3*a+1], fmaf(L22, la[3*a+2], Lz)));
                v[3*a]   = sel ? qx : v[3*a];
                v[3*a+1] = sel ? qy : v[3*a+1];
                v[3*a+2] = sel ? qz : v[3*a+2];
            }
        }

        // ---- apply backbone frame + mask ONCE per atom ----
        #pragma unroll
        for (int a = 0; a < 10; a++) {
            float mk = ((mbit >> a) & 1u) ? 1.0f : 0.0f;
            float qx = v[3*a], qy = v[3*a+1], qz = v[3*a+2];
            v[3*a]   = mk * fmaf(B00, qx, fmaf(B01, qy, fmaf(B02, qz, CAp.x)));
            v[3*a+1] = mk * fmaf(B10, qx, fmaf(B11, qy, fmaf(B12, qz, CAp.y)));
            v[3*a+2] = mk * fmaf(B20, qx, fmaf(B21, qy, fmaf(B22, qz, CAp.z)));
        }

        // ---- tile row write: 15 x ds_write_b64 ----
        float2* so2 = (float2*)&s_ot[tid * OT_STRIDE];
        #pragma unroll
        for (int k = 0; k < 15; k++)
            so2[k] = make_float2(v[2*k], v[2*k+1]);
    }

    __syncthreads();

    // ---- coalesced copy-out, division-free ----
    int m = n - i0; if (m > 256) m = 256;
    const int cnt2 = m * 21;
    float2* gout = (float2*)(out + (size_t)i0 * 42);
    const float2* bbt = (const float2*)(bb + (size_t)i0 * 12);
    int r = tid / 21;            // one magic-mul, once
    int j = tid - r * 21;
    for (int off = tid; off < cnt2; off += 256) {
        int bi = (j < 6) ? (r * 6 + j) : 0;        // clamped-safe index
        float2 gval = bbt[bi];
        int tj = (j < 6) ? 0 : (j - 6);
        const float* tp = &s_ot[r * OT_STRIDE + 2 * tj];
        float2 lval = make_float2(tp[0], tp[1]);
        gout[off] = (j < 6) ? gval : lval;
        r += 12; j += 4;                           // 256 = 12*21 + 4
        if (j >= 21) { j -= 21; r += 1; }
    }
}

extern "C" void kernel_launch(void* const* d_in, const int* in_sizes, int n_in,
                              void* d_out, int out_size, void* d_ws, size_t ws_size,
                              hipStream_t stream) {
    const int*   aa  = (const int*)d_in[0];
    const float* bb  = (const float*)d_in[1];
    const float* tor = (const float*)d_in[2];
    const float* df  = (const float*)d_in[3];
    const int*   gi  = (const int*)d_in[4];
    const float* am  = (const float*)d_in[5];
    const float* lp  = (const float*)d_in[6];
    float* outp = (float*)d_out;
    const int n = in_sizes[0];
    const int blocks = (n + 255) / 256;   // one 256-residue tile per block
    idealizer_kernel<<<blocks, 256, 0, stream>>>(aa, bb, tor, df, gi, am, lp, outp, n);
}